// Round 1
// baseline (67.239 us; speedup 1.0000x reference)
//
#include <hip/hip_runtime.h>
#include <math.h>

static constexpr int N   = 4096;  // IN_SIZE
static constexpr int H   = 5;     // HID
static constexpr int NO  = 2048;  // OUT_SIZE
static constexpr float FEPS = 1e-4f;

// ws layout (floats):
// [0          , H*N)      : W1T  [5][4096]
// [H*N        , 2*H*N)    : T    [4096][5]
// [2*H*N      , 2*H*N+H*NO): B   [5][2048]

__global__ __launch_bounds__(256) void k_w1t(const float* __restrict__ W1,
                                             float* __restrict__ W1T) {
    int idx = blockIdx.x * 256 + threadIdx.x;
    if (idx < H * N) {
        int a = idx / N;
        int j = idx - a * N;
        W1T[idx] = W1[j * H + a];   // coalesced write, strided read (tiny)
    }
}

// T[i][a] = sum_j X[i][j] * W1[j][a]; one block per row i.
__global__ __launch_bounds__(256) void k_xw1(const float* __restrict__ X,
                                             const float* __restrict__ W1T,
                                             float* __restrict__ T) {
    const int i = blockIdx.x;
    const int t = threadIdx.x;
    const float4* Xr = reinterpret_cast<const float4*>(X + (size_t)i * N);
    float acc[H] = {0.f, 0.f, 0.f, 0.f, 0.f};
#pragma unroll
    for (int c = 0; c < 4; ++c) {
        const int j4 = c * 256 + t;           // float4 index within the row
        const float4 x = Xr[j4];
#pragma unroll
        for (int a = 0; a < H; ++a) {
            const float4 w = reinterpret_cast<const float4*>(W1T + a * N)[j4];
            acc[a] += x.x * w.x + x.y * w.y + x.z * w.z + x.w * w.w;
        }
    }
    // wave reduce (width 64), then cross-wave via LDS (deterministic)
#pragma unroll
    for (int a = 0; a < H; ++a)
#pragma unroll
        for (int o = 32; o > 0; o >>= 1)
            acc[a] += __shfl_down(acc[a], o, 64);
    __shared__ float sm[4 * H];
    const int lane = t & 63, wv = t >> 6;
    if (lane == 0) {
#pragma unroll
        for (int a = 0; a < H; ++a) sm[wv * H + a] = acc[a];
    }
    __syncthreads();
    if (t < H) T[i * H + t] = sm[t] + sm[H + t] + sm[2 * H + t] + sm[3 * H + t];
}

// One block: M = W1^T T (5x5) -> Jacobi eig of M M^T (double, thread 0)
// -> y = U max(sqrt(lam),eps) U^T -> B = (y - eps*I) @ W2  (5 x 2048)
__global__ __launch_bounds__(256) void k_small(const float* __restrict__ W1,
                                               const float* __restrict__ W2,
                                               const float* __restrict__ T,
                                               float* __restrict__ B) {
    __shared__ float red[256][26];   // 25 used, pad
    __shared__ float ys[H * H];
    const int t = threadIdx.x;

    float acc[H][H];
#pragma unroll
    for (int a = 0; a < H; ++a)
#pragma unroll
        for (int b = 0; b < H; ++b) acc[a][b] = 0.f;

    for (int i = t; i < N; i += 256) {
        float w[H], tv[H];
#pragma unroll
        for (int a = 0; a < H; ++a) w[a] = W1[i * H + a];
#pragma unroll
        for (int b = 0; b < H; ++b) tv[b] = T[i * H + b];
#pragma unroll
        for (int a = 0; a < H; ++a)
#pragma unroll
            for (int b = 0; b < H; ++b) acc[a][b] += w[a] * tv[b];
    }
#pragma unroll
    for (int k = 0; k < H * H; ++k) red[t][k] = acc[k / H][k % H];
    __syncthreads();
    for (int s = 128; s > 0; s >>= 1) {
        if (t < s) {
#pragma unroll
            for (int k = 0; k < H * H; ++k) red[t][k] += red[t + s][k];
        }
        __syncthreads();
    }

    if (t == 0) {
        double Md[H][H], A[H][H], U[H][H];
        for (int a = 0; a < H; ++a)
            for (int b = 0; b < H; ++b) Md[a][b] = (double)red[0][a * H + b];
        // A = M M^T (symmetric PSD; eigvecs = left singular vecs of M)
        for (int a = 0; a < H; ++a)
            for (int b = 0; b < H; ++b) {
                double s = 0.0;
                for (int k = 0; k < H; ++k) s += Md[a][k] * Md[b][k];
                A[a][b] = s;
            }
        for (int a = 0; a < H; ++a)
            for (int b = 0; b < H; ++b) U[a][b] = (a == b) ? 1.0 : 0.0;
        // cyclic Jacobi
        for (int sweep = 0; sweep < 30; ++sweep) {
            double off = 0.0;
            for (int p = 0; p < H - 1; ++p)
                for (int q = p + 1; q < H; ++q) off += A[p][q] * A[p][q];
            if (off < 1e-24) break;
            for (int p = 0; p < H - 1; ++p)
                for (int q = p + 1; q < H; ++q) {
                    double apq = A[p][q];
                    if (fabs(apq) < 1e-30) continue;
                    double theta = (A[q][q] - A[p][p]) / (2.0 * apq);
                    double tt = ((theta >= 0.0) ? 1.0 : -1.0) /
                                (fabs(theta) + sqrt(theta * theta + 1.0));
                    double c = 1.0 / sqrt(tt * tt + 1.0);
                    double s = tt * c;
                    for (int k = 0; k < H; ++k) {   // rows p,q: R^T A
                        double apk = A[p][k], aqk = A[q][k];
                        A[p][k] = c * apk - s * aqk;
                        A[q][k] = s * apk + c * aqk;
                    }
                    for (int k = 0; k < H; ++k) {   // cols p,q: (.) R
                        double akp = A[k][p], akq = A[k][q];
                        A[k][p] = c * akp - s * akq;
                        A[k][q] = s * akp + c * akq;
                    }
                    for (int k = 0; k < H; ++k) {   // U <- U R
                        double ukp = U[k][p], ukq = U[k][q];
                        U[k][p] = c * ukp - s * ukq;
                        U[k][q] = s * ukp + c * ukq;
                    }
                }
        }
        double e[H];
        for (int k = 0; k < H; ++k) {
            double lam = A[k][k];
            if (lam < 0.0) lam = 0.0;
            double sv = sqrt(lam);
            e[k] = (sv > (double)FEPS) ? sv : (double)FEPS;
        }
        for (int a = 0; a < H; ++a)
            for (int b = 0; b < H; ++b) {
                double s = 0.0;
                for (int k = 0; k < H; ++k) s += U[a][k] * e[k] * U[b][k];
                ys[a * H + b] = (float)s;
            }
    }
    __syncthreads();

    // B[k][j] = sum_m (y[k][m] - eps*delta) * W2[m][j]
    for (int p = t; p < H * NO; p += 256) {
        const int k = p / NO;
        const int j = p - k * NO;
        float s = 0.f;
#pragma unroll
        for (int m = 0; m < H; ++m) {
            float ym = ys[k * H + m] - ((k == m) ? FEPS : 0.f);
            s += ym * W2[m * NO + j];
        }
        B[p] = s;
    }
}

// z[i][j] = sum_k W2[k][i] * B[k][j] + eps*delta_ij ; float4 per thread.
__global__ __launch_bounds__(256) void k_out(const float* __restrict__ W2,
                                             const float* __restrict__ B,
                                             float* __restrict__ Z) {
    const int gid = blockIdx.x * 256 + threadIdx.x;   // [0, 2048*512)
    const int i  = gid >> 9;          // row
    const int jj = (gid & 511) << 2;  // col (float4)
    float w[H];
#pragma unroll
    for (int k = 0; k < H; ++k) w[k] = W2[k * NO + i];
    float av[4] = {0.f, 0.f, 0.f, 0.f};
#pragma unroll
    for (int k = 0; k < H; ++k) {
        const float4 b = *reinterpret_cast<const float4*>(B + k * NO + jj);
        av[0] += w[k] * b.x;
        av[1] += w[k] * b.y;
        av[2] += w[k] * b.z;
        av[3] += w[k] * b.w;
    }
    if (i >= jj && i < jj + 4) av[i - jj] += FEPS;
    float4 o = make_float4(av[0], av[1], av[2], av[3]);
    *reinterpret_cast<float4*>(Z + (size_t)i * NO + jj) = o;
}

extern "C" void kernel_launch(void* const* d_in, const int* in_sizes, int n_in,
                              void* d_out, int out_size, void* d_ws, size_t ws_size,
                              hipStream_t stream) {
    const float* X  = (const float*)d_in[0];
    const float* W1 = (const float*)d_in[1];
    const float* W2 = (const float*)d_in[2];
    float* out = (float*)d_out;
    float* ws  = (float*)d_ws;

    float* W1T = ws;              // 5*4096
    float* T   = ws + H * N;      // 4096*5
    float* B   = ws + 2 * H * N;  // 5*2048

    hipLaunchKernelGGL(k_w1t, dim3((H * N + 255) / 256), dim3(256), 0, stream, W1, W1T);
    hipLaunchKernelGGL(k_xw1, dim3(N), dim3(256), 0, stream, X, W1T, T);
    hipLaunchKernelGGL(k_small, dim3(1), dim3(256), 0, stream, W1, W2, T, B);
    hipLaunchKernelGGL(k_out, dim3(NO * (NO / 4) / 256), dim3(256), 0, stream, W2, B, out);
}